// Round 2
// baseline (204.720 us; speedup 1.0000x reference)
//
#include <hip/hip_runtime.h>

#define NB 8
#define NC 256
#define IMG 3600
#define MP 3584         // M padded (multiple of 256)
#define NRB 28          // MP/128 row tiles (gather/des layout unit)
#define NMT 14          // MP/256 A row-tiles (mfma block rows)
#define NNT 28          // MP/128 B col-tiles (mfma block cols)
#define NKB 8           // NC/32 K-tiles of 32
#define SCALE 0.28853901f   // 0.2 * log2(e): exp(0.2*dot) = exp2(SCALE*dot)
#define LN2X2 1.38629436f   // 2*ln2: dist_diag term

typedef unsigned short u16;
typedef __bf16 bf16x8 __attribute__((ext_vector_type(8)));
typedef float  f32x4  __attribute__((ext_vector_type(4)));
typedef unsigned short u16x8 __attribute__((ext_vector_type(8)));

__device__ __forceinline__ u16 f2bf(float f) {
  unsigned u = __builtin_bit_cast(unsigned, f);
  u += 0x7FFFu + ((u >> 16) & 1u);          // round-to-nearest-even
  return (u16)(u >> 16);
}

__device__ __forceinline__ void gld16(const void* g, void* l) {
  __builtin_amdgcn_global_load_lds(
      (__attribute__((address_space(1))) void*)g,
      (__attribute__((address_space(3))) void*)l, 16, 0, 0);
}

// ---------------------------------------------------------------------------
// Gather (v2, unchanged): LDS-staged transpose so BOTH sides coalesce.
//   Block (rb,kb,side*8+b) loads 128 rows x 32 c as 16 per-c-plane coalesced
//   wave loads, packs bf16 into the bank-swizzled tile layout in LDS
//   (slot = ch ^ ((row>>1)&3)), then stores the 8KB tile as 2 contiguous
//   1KB-per-wave dwordx4 stores. Folds row/col-sum + out zeroing.
//   Rows >= M zero-filled (pad correction applied exactly in finalize).
// ---------------------------------------------------------------------------
__global__ __launch_bounds__(256)
void gather_kernel(const float* __restrict__ p1, const float* __restrict__ p2,
                   const int* __restrict__ y1, const int* __restrict__ x1,
                   const int* __restrict__ y2, const int* __restrict__ x2,
                   u16* __restrict__ des1, u16* __restrict__ des2,
                   float* __restrict__ zbase, float* __restrict__ out, int M) {
  __shared__ __align__(16) u16 tile[4096];   // 8 KB: 128 rows x 4 slots x 16B
  const int which = blockIdx.z >> 3, b = blockIdx.z & 7;
  const int kb = blockIdx.y, rb = blockIdx.x;
  const float* P = (which ? p2 : p1) + (size_t)b * NC * IMG;
  const int* Y = which ? y2 : y1;
  const int* X = which ? x2 : x1;
  u16* D = which ? des2 : des1;
  const float sc = which ? 1.f : SCALE;      // A side pre-scaled by SCALE

  const int t = threadIdx.x;

  // fold zeroing of row_sum+col_sum (2*NB*MP contiguous floats) and out
  {
    const int bid = (int)(blockIdx.z * (NKB * NRB) + blockIdx.y * NRB + blockIdx.x);
    const int gi = bid * 256 + t;
    if (gi < 2 * NB * MP) zbase[gi] = 0.f;
    if (gi == 0) *out = 0.f;
  }

  const int row = t & 127, h = t >> 7;       // h selects chunks 2h, 2h+1
  const int m = rb * 128 + row;
  const bool mv = m < M;
  const int pix = mv ? (Y[m] * 60 + X[m]) : 0;
  const float* src = P + (size_t)(kb * 32 + h * 16) * IMG + pix;

  float v[16];                               // 16 c-planes, each wave-coalesced
#pragma unroll
  for (int j = 0; j < 16; ++j) v[j] = mv ? src[(size_t)j * IMG] : 0.f;

  u16x8 lo, hi;
#pragma unroll
  for (int j = 0; j < 8; ++j) lo[j] = f2bf(v[j] * sc);
#pragma unroll
  for (int j = 0; j < 8; ++j) hi[j] = f2bf(v[8 + j] * sc);

  const int sw = (row >> 1) & 3;
  *(u16x8*)&tile[((row * 4) + ((2 * h)     ^ sw)) * 8] = lo;
  *(u16x8*)&tile[((row * 4) + ((2 * h + 1) ^ sw)) * 8] = hi;
  __syncthreads();

  // linear LDS -> linear global: 2 x (64 lanes x 16B contiguous) per wave
  u16* Dt = D + (((size_t)b * NKB + kb) * NRB + rb) * 4096;
  *(u16x8*)(Dt + t * 8)         = *(const u16x8*)&tile[t * 8];
  *(u16x8*)(Dt + (t + 256) * 8) = *(const u16x8*)&tile[(t + 256) * 8];
}

// ---------------------------------------------------------------------------
// MFMA GEMM + fused exp2 / row / col / diag.   v3: 256x128 C-tile, 512 thr.
//   8 waves in 4x2 grid (wm 0..3, wn 0..1), per-wave 64x64 tile = the SAME
//   verified frag/epilogue code as v1/v2. Per block-step stages 24 KB (A 16 +
//   B 8) for 2x the MFMA work of the 128x128 tile -> per-SIMD MFMA (1242 cyc)
//   now dominates LDS (~690 cyc) per CU-round. VGPR ~64+32+misc <= 128 ->
//   4 waves/SIMD; LDS 3x24 KB = 72 KB -> exactly 2 blocks/CU (144 <= 160 KB).
//   K-loop: single barrier per step + 3-buffer rotation, 2-deep prefetch:
//   iter k: vmcnt(3) [own stage(k) loads retired; vmcnt retires in order] ->
//   s_barrier [ALL waves' stage(k) resident AND all waves' k-1 frag reads
//   complete (lgkmcnt enforced before their MFMAs issued) => staging k+2 over
//   buf[(k-1)%3] is WAR-safe] -> stage(k+2) -> frags k -> 16 MFMAs.
//   Never vmcnt(0) until the last iter; prefetch distance = 2 full steps.
//   A-tile 256 rows = 2 adjacent 128-row des tiles (contiguous in memory);
//   frag address (row*4+slot)*8 valid for row 0..255 since halves are
//   contiguous 4KB blocks. All register-array subscripts COMPILE-TIME.
//   Frag layouts (16x16x32 bf16): A/B[row=l15][k=quad*8+j]; C/D col=l15,
//   row=quad*4+reg.
// ---------------------------------------------------------------------------
__global__ __launch_bounds__(512, 4)
void mfma_lse(const u16* __restrict__ des1, const u16* __restrict__ des2,
              float* __restrict__ row_sum, float* __restrict__ col_sum,
              float* __restrict__ diag, int M) {
  __shared__ __align__(16) u16 bufA[3][8192];   // 16 KB each: 256 rows
  __shared__ __align__(16) u16 bufB[3][4096];   // 8 KB each: 128 rows

  const int flat = blockIdx.x;
  const int b = flat & 7;
  const int f = flat >> 3;                      // 0..391
  const int mt = f % NMT;                       // 0..13
  const int nt = (f / NMT + 2 * mt) % NNT;      // 0..27, stagger col-atomics
  const int t = threadIdx.x;
  const int w = t >> 6, lane = t & 63;
  const int wm = w >> 1, wn = w & 1;            // 4x2 wave grid
  const int quad = lane >> 4, l15 = lane & 15;

  auto stage = [&](int kb, int sel) {
    const u16* Ak = des1 + (((size_t)b * NKB + kb) * NRB + 2 * mt) * 4096;
    const u16* Bk = des2 + (((size_t)b * NKB + kb) * NRB + nt) * 4096;
    gld16(Ak + (size_t)t * 8,         &bufA[sel][t * 8]);
    gld16(Ak + (size_t)(t + 512) * 8, &bufA[sel][(t + 512) * 8]);
    gld16(Bk + (size_t)t * 8,         &bufB[sel][t * 8]);
  };

  f32x4 acc[4][4] = {};

  stage(0, 0);
  stage(1, 1);
#pragma unroll
  for (int kb = 0; kb < NKB; ++kb) {
    if (kb + 1 < NKB) {
      asm volatile("s_waitcnt vmcnt(3)" ::: "memory");  // stage(kb) resident
    } else {
      asm volatile("s_waitcnt vmcnt(0)" ::: "memory");  // last: drain all
    }
    asm volatile("s_barrier" ::: "memory");
    if (kb + 2 < NKB) stage(kb + 2, (kb + 2) % 3);

    const u16* As = bufA[kb % 3];
    const u16* Bs = bufB[kb % 3];
    bf16x8 af[4], bf[4];
#pragma unroll
    for (int i = 0; i < 4; ++i) {
      int row = wm * 64 + i * 16 + l15;         // 0..255
      int slot = quad ^ ((row >> 1) & 3);
      af[i] = *(const bf16x8*)&As[(row * 4 + slot) * 8];
    }
#pragma unroll
    for (int j = 0; j < 4; ++j) {
      int row = wn * 64 + j * 16 + l15;         // 0..127
      int slot = quad ^ ((row >> 1) & 3);
      bf[j] = *(const bf16x8*)&Bs[(row * 4 + slot) * 8];
    }
#pragma unroll
    for (int i = 0; i < 4; ++i)
#pragma unroll
      for (int j = 0; j < 4; ++j)
        acc[i][j] = __builtin_amdgcn_mfma_f32_16x16x32_bf16(
            af[i], bf[j], acc[i][j], 0, 0, 0);
  }

  // ---- lean epilogue: bare exp2, no masks, shuffle-reduced atomics ----
  // pad rows/cols are zero -> exp2(0)=1; exact constant subtracted in finalize
  const int rbase = (size_t)0 + mt * 256 + wm * 64;
  float cp[4] = {0.f, 0.f, 0.f, 0.f};
#pragma unroll
  for (int i = 0; i < 4; ++i)
#pragma unroll
    for (int r = 0; r < 4; ++r) {
      float rv = 0.f;
#pragma unroll
      for (int j = 0; j < 4; ++j) {
        float e = exp2f(acc[i][j][r]);
        rv += e;
        cp[j] += e;
      }
      rv += __shfl_xor(rv, 1); rv += __shfl_xor(rv, 2);
      rv += __shfl_xor(rv, 4); rv += __shfl_xor(rv, 8);
      if (l15 == 0)
        atomicAdd(&row_sum[(size_t)b * MP + rbase + i * 16 + quad * 4 + r], rv);
    }
#pragma unroll
  for (int j = 0; j < 4; ++j) {
    float c = cp[j];
    c += __shfl_xor(c, 16); c += __shfl_xor(c, 32);
    if (quad == 0)
      atomicAdd(&col_sum[(size_t)b * MP + nt * 128 + wn * 64 + j * 16 + l15], c);
  }
  // diagonal 64x64 tile g (0..55): rows [g*64,+64) == cols [g*64,+64)
  // handled by the unique block/wave with mt*4+wm == nt*2+wn
  if (mt * 4 + wm == nt * 2 + wn) {
#pragma unroll
    for (int i = 0; i < 4; ++i)
#pragma unroll
      for (int r = 0; r < 4; ++r)
        if (l15 == quad * 4 + r)
          diag[(size_t)b * MP + rbase + i * 16 + quad * 4 + r] = acc[i][i][r];
  }
}

// ---------------------------------------------------------------------------
// loss = mean over valid of log(rs - pad) + log(cs - pad) - 2*ln2*diag'
// pad = MP - M exact (pad rows/cols contributed exp2(0)=1 each).
// ---------------------------------------------------------------------------
__global__ __launch_bounds__(256)
void finalize(const float* __restrict__ row_sum, const float* __restrict__ col_sum,
              const float* __restrict__ diag, float* __restrict__ out,
              int M, float padf, float inv_total) {
  __shared__ float red[4];
  const int i = blockIdx.x * 256 + threadIdx.x;   // over NB*MP
  const int mm = i % MP;
  float s = 0.f;
  if (mm < M)
    s = __logf(row_sum[i] - padf) + __logf(col_sum[i] - padf) - LN2X2 * diag[i];
#pragma unroll
  for (int o = 1; o < 64; o <<= 1) s += __shfl_xor(s, o);
  const int lane = threadIdx.x & 63, wid = threadIdx.x >> 6;
  if (lane == 0) red[wid] = s;
  __syncthreads();
  if (threadIdx.x == 0)
    atomicAdd(out, (red[0] + red[1] + red[2] + red[3]) * inv_total);
}

extern "C" void kernel_launch(void* const* d_in, const int* in_sizes, int n_in,
                              void* d_out, int out_size, void* d_ws, size_t ws_size,
                              hipStream_t stream) {
  const float* p1 = (const float*)d_in[0];
  const float* p2 = (const float*)d_in[1];
  const int* y1 = (const int*)d_in[2];
  const int* x1 = (const int*)d_in[3];
  const int* y2 = (const int*)d_in[4];
  const int* x2 = (const int*)d_in[5];
  const int M = in_sizes[2];                    // 3540 (<= MP)

  float* row_sum = (float*)d_ws;                // NB*MP
  float* col_sum = row_sum + (size_t)NB * MP;   // NB*MP
  float* diagbuf = col_sum + (size_t)NB * MP;   // NB*MP
  size_t off = (((size_t)3 * NB * MP * sizeof(float)) + 255) & ~(size_t)255;
  u16* des1 = (u16*)((char*)d_ws + off);        // NB*MP*NC bf16, tiled+swizzled
  u16* des2 = des1 + (size_t)NB * MP * NC;

  // zeroing of row/col sums + out folded into gather_kernel (fewer graph nodes)
  dim3 ggrid(NRB, NKB, 2 * NB);                 // (28, 8, 16) = 3584 tiles
  gather_kernel<<<ggrid, 256, 0, stream>>>(p1, p2, y1, x1, y2, x2, des1, des2,
                                           row_sum, (float*)d_out, M);

  mfma_lse<<<dim3(NB * NMT * NNT), 512, 0, stream>>>(des1, des2, row_sum,
                                                     col_sum, diagbuf, M);

  finalize<<<(NB * MP) / 256, 256, 0, stream>>>(row_sum, col_sum, diagbuf,
                                                (float*)d_out, M,
                                                (float)(MP - M),
                                                1.f / (float)(NB * M));
}

// Round 3
// 193.997 us; speedup vs baseline: 1.0553x; 1.0553x over previous
//
#include <hip/hip_runtime.h>

#define NB 8
#define NC 256
#define IMG 3600
#define MP 3584         // M padded (multiple of 256)
#define NRB 28          // MP/128 row tiles (gather/des layout unit)
#define NMT 14          // MP/256 A row-tiles (mfma block rows)
#define NNT 28          // MP/128 B col-tiles (mfma block cols)
#define NKB 8           // NC/32 K-tiles of 32
#define SCALE 0.28853901f   // 0.2 * log2(e): exp(0.2*dot) = exp2(SCALE*dot)
#define LN2X2 1.38629436f   // 2*ln2: dist_diag term

typedef unsigned short u16;
typedef __bf16 bf16x8 __attribute__((ext_vector_type(8)));
typedef float  f32x4  __attribute__((ext_vector_type(4)));
typedef unsigned short u16x8 __attribute__((ext_vector_type(8)));

__device__ __forceinline__ u16 f2bf(float f) {
  unsigned u = __builtin_bit_cast(unsigned, f);
  u += 0x7FFFu + ((u >> 16) & 1u);          // round-to-nearest-even
  return (u16)(u >> 16);
}

__device__ __forceinline__ void gld16(const void* g, void* l) {
  __builtin_amdgcn_global_load_lds(
      (__attribute__((address_space(1))) void*)g,
      (__attribute__((address_space(3))) void*)l, 16, 0, 0);
}

// ---------------------------------------------------------------------------
// Gather (v2, unchanged): LDS-staged transpose so BOTH sides coalesce.
//   Block (rb,kb,side*8+b) loads 128 rows x 32 c as 16 per-c-plane coalesced
//   wave loads, packs bf16 into the bank-swizzled tile layout in LDS
//   (slot = ch ^ ((row>>1)&3)), then stores the 8KB tile as 2 contiguous
//   1KB-per-wave dwordx4 stores. Folds row/col-sum + out zeroing.
//   Rows >= M zero-filled (pad correction applied exactly in finalize).
// ---------------------------------------------------------------------------
__global__ __launch_bounds__(256)
void gather_kernel(const float* __restrict__ p1, const float* __restrict__ p2,
                   const int* __restrict__ y1, const int* __restrict__ x1,
                   const int* __restrict__ y2, const int* __restrict__ x2,
                   u16* __restrict__ des1, u16* __restrict__ des2,
                   float* __restrict__ zbase, float* __restrict__ out, int M) {
  __shared__ __align__(16) u16 tile[4096];   // 8 KB: 128 rows x 4 slots x 16B
  const int which = blockIdx.z >> 3, b = blockIdx.z & 7;
  const int kb = blockIdx.y, rb = blockIdx.x;
  const float* P = (which ? p2 : p1) + (size_t)b * NC * IMG;
  const int* Y = which ? y2 : y1;
  const int* X = which ? x2 : x1;
  u16* D = which ? des2 : des1;
  const float sc = which ? 1.f : SCALE;      // A side pre-scaled by SCALE

  const int t = threadIdx.x;

  // fold zeroing of row_sum+col_sum (2*NB*MP contiguous floats) and out
  {
    const int bid = (int)(blockIdx.z * (NKB * NRB) + blockIdx.y * NRB + blockIdx.x);
    const int gi = bid * 256 + t;
    if (gi < 2 * NB * MP) zbase[gi] = 0.f;
    if (gi == 0) *out = 0.f;
  }

  const int row = t & 127, h = t >> 7;       // h selects chunks 2h, 2h+1
  const int m = rb * 128 + row;
  const bool mv = m < M;
  const int pix = mv ? (Y[m] * 60 + X[m]) : 0;
  const float* src = P + (size_t)(kb * 32 + h * 16) * IMG + pix;

  float v[16];                               // 16 c-planes, each wave-coalesced
#pragma unroll
  for (int j = 0; j < 16; ++j) v[j] = mv ? src[(size_t)j * IMG] : 0.f;

  u16x8 lo, hi;
#pragma unroll
  for (int j = 0; j < 8; ++j) lo[j] = f2bf(v[j] * sc);
#pragma unroll
  for (int j = 0; j < 8; ++j) hi[j] = f2bf(v[8 + j] * sc);

  const int sw = (row >> 1) & 3;
  *(u16x8*)&tile[((row * 4) + ((2 * h)     ^ sw)) * 8] = lo;
  *(u16x8*)&tile[((row * 4) + ((2 * h + 1) ^ sw)) * 8] = hi;
  __syncthreads();

  // linear LDS -> linear global: 2 x (64 lanes x 16B contiguous) per wave
  u16* Dt = D + (((size_t)b * NKB + kb) * NRB + rb) * 4096;
  *(u16x8*)(Dt + t * 8)         = *(const u16x8*)&tile[t * 8];
  *(u16x8*)(Dt + (t + 256) * 8) = *(const u16x8*)&tile[(t + 256) * 8];
}

// ---------------------------------------------------------------------------
// MFMA GEMM + fused exp2 / row / col / diag.
// v4: 256x128 block tile, 256 THREADS, fat 128x64 wave tiles (2x2 waves).
//   Rationale (R2 post-mortem): v1 resource split was MFMA 26% / LDS-read 37%
//   / LDS-write 18% -> LDS pipe is the binding throughput resource once
//   overlap improves; and reg cliffs at 128 arch regs killed v2/v3 (v3
//   spilled: 125MB scratch writes). So: wave tile 128x64 -> 12 ds_read_b128
//   feed 32 MFMAs (2.67 vs 2.0 MFMA/read, -25% LDS bytes/FLOP), acc[8][4] =
//   128 VGPR + frags 48 + addr ~25 = ~200 regs, comfortably under the 256
//   budget of launch_bounds(256,2) -> 2 waves/SIMD, NO spill (deliberately
//   off the 128-reg knife edge).
//   K-loop: single barrier per step, 3-buffer rotation, prefetch distance 2:
//   iter k: vmcnt(6) [stage(k) resident; 12 outstanding, wait 6 oldest] ->
//   s_barrier [all waves' stage(k) resident AND k-1 frag reads consumed
//   (lgkm waits precede their MFMAs) => staging k+2 over buf[(k-1)%3] is
//   WAR-safe; gld16 of stage(k+2) issues only after all waves pass barrier]
//   -> stage(k+2) -> 12 frag ds_read_b128 -> 32 MFMAs. Never vmcnt(0) until
//   the last iter. LDS 3 x (16+8) KB = 72 KB -> 2 blocks/CU (144 <= 160).
//   A-tile 256 rows = 2 adjacent contiguous 128-row des tiles. All register
//   subscripts COMPILE-TIME. Frag layouts (16x16x32 bf16): A/B[row=l15]
//   [k=quad*8+j]; C/D col=l15, row=quad*4+reg.
// ---------------------------------------------------------------------------
__global__ __launch_bounds__(256, 2)
void mfma_lse(const u16* __restrict__ des1, const u16* __restrict__ des2,
              float* __restrict__ row_sum, float* __restrict__ col_sum,
              float* __restrict__ diag, int M) {
  __shared__ __align__(16) u16 bufA[3][8192];   // 16 KB each: 256 rows
  __shared__ __align__(16) u16 bufB[3][4096];   // 8 KB each: 128 rows

  const int flat = blockIdx.x;
  const int b = flat & 7;
  const int f = flat >> 3;                      // 0..391
  const int mt = f % NMT;                       // 0..13
  const int nt = (f / NMT + 2 * mt) % NNT;      // 0..27, stagger col-atomics
  const int t = threadIdx.x;
  const int w = t >> 6, lane = t & 63;
  const int wm = w >> 1, wn = w & 1;            // 2x2 wave grid
  const int quad = lane >> 4, l15 = lane & 15;

  auto stage = [&](int kb, int sel) {
    const u16* Ak = des1 + (((size_t)b * NKB + kb) * NRB + 2 * mt) * 4096;
    const u16* Bk = des2 + (((size_t)b * NKB + kb) * NRB + nt) * 4096;
#pragma unroll
    for (int i = 0; i < 4; ++i) {
      int idx = i * 256 + t;
      gld16(Ak + (size_t)idx * 8, &bufA[sel][idx * 8]);
    }
#pragma unroll
    for (int i = 0; i < 2; ++i) {
      int idx = i * 256 + t;
      gld16(Bk + (size_t)idx * 8, &bufB[sel][idx * 8]);
    }
  };

  f32x4 acc[8][4] = {};

  stage(0, 0);
  stage(1, 1);
#pragma unroll
  for (int kb = 0; kb < NKB; ++kb) {
    if (kb + 1 < NKB) {
      asm volatile("s_waitcnt vmcnt(6)" ::: "memory");  // stage(kb) resident
    } else {
      asm volatile("s_waitcnt vmcnt(0)" ::: "memory");  // last: drain all
    }
    asm volatile("s_barrier" ::: "memory");
    if (kb + 2 < NKB) stage(kb + 2, (kb + 2) % 3);

    const u16* As = bufA[kb % 3];
    const u16* Bs = bufB[kb % 3];
    bf16x8 af[8], bf[4];
#pragma unroll
    for (int i = 0; i < 8; ++i) {
      int row = wm * 128 + i * 16 + l15;        // 0..255
      int slot = quad ^ ((row >> 1) & 3);
      af[i] = *(const bf16x8*)&As[(row * 4 + slot) * 8];
    }
#pragma unroll
    for (int j = 0; j < 4; ++j) {
      int row = wn * 64 + j * 16 + l15;         // 0..127
      int slot = quad ^ ((row >> 1) & 3);
      bf[j] = *(const bf16x8*)&Bs[(row * 4 + slot) * 8];
    }
#pragma unroll
    for (int i = 0; i < 8; ++i)
#pragma unroll
      for (int j = 0; j < 4; ++j)
        acc[i][j] = __builtin_amdgcn_mfma_f32_16x16x32_bf16(
            af[i], bf[j], acc[i][j], 0, 0, 0);
  }

  // ---- lean epilogue: bare exp2, no masks, shuffle-reduced atomics ----
  // pad rows/cols are zero -> exp2(0)=1; exact constant subtracted in finalize
  const int rbase = mt * 256 + wm * 128;
  float cp[4] = {0.f, 0.f, 0.f, 0.f};
#pragma unroll
  for (int i = 0; i < 8; ++i)
#pragma unroll
    for (int r = 0; r < 4; ++r) {
      float rv = 0.f;
#pragma unroll
      for (int j = 0; j < 4; ++j) {
        float e = exp2f(acc[i][j][r]);
        rv += e;
        cp[j] += e;
      }
      rv += __shfl_xor(rv, 1); rv += __shfl_xor(rv, 2);
      rv += __shfl_xor(rv, 4); rv += __shfl_xor(rv, 8);
      if (l15 == 0)
        atomicAdd(&row_sum[(size_t)b * MP + rbase + i * 16 + quad * 4 + r], rv);
    }
#pragma unroll
  for (int j = 0; j < 4; ++j) {
    float c = cp[j];
    c += __shfl_xor(c, 16); c += __shfl_xor(c, 32);
    if (quad == 0)
      atomicAdd(&col_sum[(size_t)b * MP + nt * 128 + wn * 64 + j * 16 + l15], c);
  }
  // diagonal 64x64 sub-tiles: wave rows span 64-tiles {mt*4+wm*2+h, h=0,1},
  // cols span 64-tile nt*2+wn. On match, diag elems: i=h*4+j, quad*4+r==l15.
#pragma unroll
  for (int h = 0; h < 2; ++h)
    if (mt * 4 + wm * 2 + h == nt * 2 + wn) {
#pragma unroll
      for (int j = 0; j < 4; ++j)
#pragma unroll
        for (int r = 0; r < 4; ++r)
          if (l15 == quad * 4 + r)
            diag[(size_t)b * MP + rbase + h * 64 + j * 16 + quad * 4 + r] =
                acc[h * 4 + j][j][r];
    }
}

// ---------------------------------------------------------------------------
// loss = mean over valid of log(rs - pad) + log(cs - pad) - 2*ln2*diag'
// pad = MP - M exact (pad rows/cols contributed exp2(0)=1 each).
// ---------------------------------------------------------------------------
__global__ __launch_bounds__(256)
void finalize(const float* __restrict__ row_sum, const float* __restrict__ col_sum,
              const float* __restrict__ diag, float* __restrict__ out,
              int M, float padf, float inv_total) {
  __shared__ float red[4];
  const int i = blockIdx.x * 256 + threadIdx.x;   // over NB*MP
  const int mm = i % MP;
  float s = 0.f;
  if (mm < M)
    s = __logf(row_sum[i] - padf) + __logf(col_sum[i] - padf) - LN2X2 * diag[i];
#pragma unroll
  for (int o = 1; o < 64; o <<= 1) s += __shfl_xor(s, o);
  const int lane = threadIdx.x & 63, wid = threadIdx.x >> 6;
  if (lane == 0) red[wid] = s;
  __syncthreads();
  if (threadIdx.x == 0)
    atomicAdd(out, (red[0] + red[1] + red[2] + red[3]) * inv_total);
}

extern "C" void kernel_launch(void* const* d_in, const int* in_sizes, int n_in,
                              void* d_out, int out_size, void* d_ws, size_t ws_size,
                              hipStream_t stream) {
  const float* p1 = (const float*)d_in[0];
  const float* p2 = (const float*)d_in[1];
  const int* y1 = (const int*)d_in[2];
  const int* x1 = (const int*)d_in[3];
  const int* y2 = (const int*)d_in[4];
  const int* x2 = (const int*)d_in[5];
  const int M = in_sizes[2];                    // 3540 (<= MP)

  float* row_sum = (float*)d_ws;                // NB*MP
  float* col_sum = row_sum + (size_t)NB * MP;   // NB*MP
  float* diagbuf = col_sum + (size_t)NB * MP;   // NB*MP
  size_t off = (((size_t)3 * NB * MP * sizeof(float)) + 255) & ~(size_t)255;
  u16* des1 = (u16*)((char*)d_ws + off);        // NB*MP*NC bf16, tiled+swizzled
  u16* des2 = des1 + (size_t)NB * MP * NC;

  // zeroing of row/col sums + out folded into gather_kernel (fewer graph nodes)
  dim3 ggrid(NRB, NKB, 2 * NB);                 // (28, 8, 16) = 3584 tiles
  gather_kernel<<<ggrid, 256, 0, stream>>>(p1, p2, y1, x1, y2, x2, des1, des2,
                                           row_sum, (float*)d_out, M);

  mfma_lse<<<dim3(NB * NMT * NNT), 256, 0, stream>>>(des1, des2, row_sum,
                                                     col_sum, diagbuf, M);

  finalize<<<(NB * MP) / 256, 256, 0, stream>>>(row_sum, col_sum, diagbuf,
                                                (float*)d_out, M,
                                                (float)(MP - M),
                                                1.f / (float)(NB * M));
}

// Round 4
// 189.612 us; speedup vs baseline: 1.0797x; 1.0231x over previous
//
#include <hip/hip_runtime.h>

#define NB 8
#define NC 256
#define IMG 3600
#define MP 3584         // M padded (multiple of 128)
#define NRB 28          // MP/128 row/col tiles
#define NKB 8           // NC/32 K-tiles of 32
#define SCALE 0.28853901f   // 0.2 * log2(e): exp(0.2*dot) = exp2(SCALE*dot)
#define LN2X2 1.38629436f   // 2*ln2: dist_diag term

typedef unsigned short u16;
typedef __bf16 bf16x8 __attribute__((ext_vector_type(8)));
typedef float  f32x4  __attribute__((ext_vector_type(4)));
typedef unsigned short u16x8 __attribute__((ext_vector_type(8)));

__device__ __forceinline__ u16 f2bf(float f) {
  unsigned u = __builtin_bit_cast(unsigned, f);
  u += 0x7FFFu + ((u >> 16) & 1u);          // round-to-nearest-even
  return (u16)(u >> 16);
}

// ---------------------------------------------------------------------------
// Gather (v2, unchanged): LDS-staged transpose so BOTH sides coalesce.
//   Block (rb,kb,side*8+b) loads 128 rows x 32 c as 16 per-c-plane coalesced
//   wave loads, packs bf16 into the slot-swizzled tile layout in LDS
//   (slot = ch ^ ((row>>1)&3)), then stores the 8KB tile as 2 contiguous
//   1KB-per-wave dwordx4 stores. Folds row/col-sum + out zeroing.
//   Rows >= M zero-filled (pad correction applied exactly in finalize).
// ---------------------------------------------------------------------------
__global__ __launch_bounds__(256)
void gather_kernel(const float* __restrict__ p1, const float* __restrict__ p2,
                   const int* __restrict__ y1, const int* __restrict__ x1,
                   const int* __restrict__ y2, const int* __restrict__ x2,
                   u16* __restrict__ des1, u16* __restrict__ des2,
                   float* __restrict__ zbase, float* __restrict__ out, int M) {
  __shared__ __align__(16) u16 tile[4096];   // 8 KB: 128 rows x 4 slots x 16B
  const int which = blockIdx.z >> 3, b = blockIdx.z & 7;
  const int kb = blockIdx.y, rb = blockIdx.x;
  const float* P = (which ? p2 : p1) + (size_t)b * NC * IMG;
  const int* Y = which ? y2 : y1;
  const int* X = which ? x2 : x1;
  u16* D = which ? des2 : des1;
  const float sc = which ? 1.f : SCALE;      // A side pre-scaled by SCALE

  const int t = threadIdx.x;

  // fold zeroing of row_sum+col_sum (2*NB*MP contiguous floats) and out
  {
    const int bid = (int)(blockIdx.z * (NKB * NRB) + blockIdx.y * NRB + blockIdx.x);
    const int gi = bid * 256 + t;
    if (gi < 2 * NB * MP) zbase[gi] = 0.f;
    if (gi == 0) *out = 0.f;
  }

  const int row = t & 127, h = t >> 7;       // h selects chunks 2h, 2h+1
  const int m = rb * 128 + row;
  const bool mv = m < M;
  const int pix = mv ? (Y[m] * 60 + X[m]) : 0;
  const float* src = P + (size_t)(kb * 32 + h * 16) * IMG + pix;

  float v[16];                               // 16 c-planes, each wave-coalesced
#pragma unroll
  for (int j = 0; j < 16; ++j) v[j] = mv ? src[(size_t)j * IMG] : 0.f;

  u16x8 lo, hi;
#pragma unroll
  for (int j = 0; j < 8; ++j) lo[j] = f2bf(v[j] * sc);
#pragma unroll
  for (int j = 0; j < 8; ++j) hi[j] = f2bf(v[8 + j] * sc);

  const int sw = (row >> 1) & 3;
  *(u16x8*)&tile[((row * 4) + ((2 * h)     ^ sw)) * 8] = lo;
  *(u16x8*)&tile[((row * 4) + ((2 * h + 1) ^ sw)) * 8] = hi;
  __syncthreads();

  // linear LDS -> linear global: 2 x (64 lanes x 16B contiguous) per wave
  u16* Dt = D + (((size_t)b * NKB + kb) * NRB + rb) * 4096;
  *(u16x8*)(Dt + t * 8)         = *(const u16x8*)&tile[t * 8];
  *(u16x8*)(Dt + (t + 256) * 8) = *(const u16x8*)&tile[(t + 256) * 8];
}

// ---------------------------------------------------------------------------
// MFMA GEMM + fused exp2 / row / col / diag.
// v5 FLATMM: zero LDS, zero barriers. Fragments load DIRECTLY from des
//   (L2-resident, XCD-pinned by b=flat&7) into VGPRs, register
//   double-buffered one K-step ahead; compiler inserts precise counted
//   vmcnt per first use (no barrier -> no vmcnt(0) drain anywhere).
//   Rationale (R3 post-mortem): v1's LDS pipe was ~50% busy and the
//   barrier<->LDS<->MFMA chain latency-bound; every occupancy drop lost.
//   Here: 12 independent waves/CU (launch_bounds(256,3), ~145 regs, no LDS
//   cap), each wave 64x64 tile exactly as v1 (proven epilogue reused).
//   Address algebra: frag i of A = Abase_kb + offA + i*1024B where
//   offA = row*64 + slot*16, row = wm*64+l15, slot = quad^((row>>1)&3);
//   slot is i-invariant since (16i)>>1 = 0 mod 4. Each frag load: 64 lanes
//   cover one full contiguous 1KB block -> perfectly coalesced
//   global_load_dwordx4 with immediate offsets; per-step cost = 1 scalar
//   base bump. Block's 4 waves (2x2) share A/B 4KB slices pairwise within
//   a ~300-cyc window -> L1 (32KB) absorbs much of the 2x duplication;
//   worst case pure-L2 ~1.6GB at 34.5 TB/s = 45us.
//   All register-array subscripts COMPILE-TIME (kb-loop fully unrolled).
//   Frag layouts (16x16x32 bf16): A/B[row=l15][k=quad*8+j]; C/D col=l15,
//   row=quad*4+reg.
// ---------------------------------------------------------------------------
__global__ __launch_bounds__(256, 3)
void mfma_lse(const u16* __restrict__ des1, const u16* __restrict__ des2,
              float* __restrict__ row_sum, float* __restrict__ col_sum,
              float* __restrict__ diag, int M) {
  const int flat = blockIdx.x;
  const int b = flat & 7;                       // XCD-pinned batch
  const int f = flat >> 3;
  const int mt = f % NRB;
  const int nt = (f / NRB + mt) % NRB;          // stagger col-atomic order
  const int m0 = mt * 128, n0 = nt * 128;
  const int t = threadIdx.x;
  const int w = t >> 6, lane = t & 63;
  const int wm = w >> 1, wn = w & 1;
  const int quad = lane >> 4, l15 = lane & 15;

  // per-lane byte offsets into one 8KB des tile (slot swizzle folded in)
  const int ra = wm * 64 + l15;
  const int rbw = wn * 64 + l15;
  const int offA = ra * 64 + (quad ^ ((ra >> 1) & 3)) * 16;
  const int offB = rbw * 64 + (quad ^ ((rbw >> 1) & 3)) * 16;

  const char* Abase = (const char*)(des1 + (((size_t)b * NKB) * NRB + mt) * 4096) + offA;
  const char* Bbase = (const char*)(des2 + (((size_t)b * NKB) * NRB + nt) * 4096) + offB;
  const size_t kstride = (size_t)NRB * 4096 * sizeof(u16);  // bytes per kb

  bf16x8 af[2][4], bf[2][4];
  auto load = [&](int kb, int sel) {
    const char* Ak = Abase + (size_t)kb * kstride;
    const char* Bk = Bbase + (size_t)kb * kstride;
#pragma unroll
    for (int i = 0; i < 4; ++i) {
      af[sel][i] = *(const bf16x8*)(Ak + i * 1024);
      bf[sel][i] = *(const bf16x8*)(Bk + i * 1024);
    }
  };

  f32x4 acc[4][4] = {};

  load(0, 0);
#pragma unroll
  for (int kb = 0; kb < NKB; ++kb) {
    if (kb + 1 < NKB) load(kb + 1, (kb + 1) & 1);
    const int s = kb & 1;                       // compile-time after unroll
#pragma unroll
    for (int i = 0; i < 4; ++i)
#pragma unroll
      for (int j = 0; j < 4; ++j)
        acc[i][j] = __builtin_amdgcn_mfma_f32_16x16x32_bf16(
            af[s][i], bf[s][j], acc[i][j], 0, 0, 0);
  }

  // ---- lean epilogue (v1-proven): bare exp2, no masks, shuffle atomics ----
  // pad rows/cols are zero -> exp2(0)=1; exact constant subtracted in finalize
  float cp[4] = {0.f, 0.f, 0.f, 0.f};
#pragma unroll
  for (int i = 0; i < 4; ++i)
#pragma unroll
    for (int r = 0; r < 4; ++r) {
      float rv = 0.f;
#pragma unroll
      for (int j = 0; j < 4; ++j) {
        float e = exp2f(acc[i][j][r]);
        rv += e;
        cp[j] += e;
      }
      rv += __shfl_xor(rv, 1); rv += __shfl_xor(rv, 2);
      rv += __shfl_xor(rv, 4); rv += __shfl_xor(rv, 8);
      if (l15 == 0)
        atomicAdd(&row_sum[(size_t)b * MP + m0 + wm * 64 + i * 16 + quad * 4 + r], rv);
    }
#pragma unroll
  for (int j = 0; j < 4; ++j) {
    float c = cp[j];
    c += __shfl_xor(c, 16); c += __shfl_xor(c, 32);
    if (quad == 0)
      atomicAdd(&col_sum[(size_t)b * MP + n0 + wn * 64 + j * 16 + l15], c);
  }
  if (mt == nt && wm == wn) {
#pragma unroll
    for (int i = 0; i < 4; ++i)
#pragma unroll
      for (int r = 0; r < 4; ++r)
        if (l15 == quad * 4 + r)
          diag[(size_t)b * MP + m0 + wm * 64 + i * 16 + quad * 4 + r] =
              acc[i][i][r];
  }
}

// ---------------------------------------------------------------------------
// loss = mean over valid of log(rs - pad) + log(cs - pad) - 2*ln2*diag'
// pad = MP - M exact (pad rows/cols contributed exp2(0)=1 each).
// ---------------------------------------------------------------------------
__global__ __launch_bounds__(256)
void finalize(const float* __restrict__ row_sum, const float* __restrict__ col_sum,
              const float* __restrict__ diag, float* __restrict__ out,
              int M, float padf, float inv_total) {
  __shared__ float red[4];
  const int i = blockIdx.x * 256 + threadIdx.x;   // over NB*MP
  const int mm = i % MP;
  float s = 0.f;
  if (mm < M)
    s = __logf(row_sum[i] - padf) + __logf(col_sum[i] - padf) - LN2X2 * diag[i];
#pragma unroll
  for (int o = 1; o < 64; o <<= 1) s += __shfl_xor(s, o);
  const int lane = threadIdx.x & 63, wid = threadIdx.x >> 6;
  if (lane == 0) red[wid] = s;
  __syncthreads();
  if (threadIdx.x == 0)
    atomicAdd(out, (red[0] + red[1] + red[2] + red[3]) * inv_total);
}

extern "C" void kernel_launch(void* const* d_in, const int* in_sizes, int n_in,
                              void* d_out, int out_size, void* d_ws, size_t ws_size,
                              hipStream_t stream) {
  const float* p1 = (const float*)d_in[0];
  const float* p2 = (const float*)d_in[1];
  const int* y1 = (const int*)d_in[2];
  const int* x1 = (const int*)d_in[3];
  const int* y2 = (const int*)d_in[4];
  const int* x2 = (const int*)d_in[5];
  const int M = in_sizes[2];                    // 3540 (<= MP)

  float* row_sum = (float*)d_ws;                // NB*MP
  float* col_sum = row_sum + (size_t)NB * MP;   // NB*MP
  float* diagbuf = col_sum + (size_t)NB * MP;   // NB*MP
  size_t off = (((size_t)3 * NB * MP * sizeof(float)) + 255) & ~(size_t)255;
  u16* des1 = (u16*)((char*)d_ws + off);        // NB*MP*NC bf16, tiled+swizzled
  u16* des2 = des1 + (size_t)NB * MP * NC;

  // zeroing of row/col sums + out folded into gather_kernel (fewer graph nodes)
  dim3 ggrid(NRB, NKB, 2 * NB);                 // (28, 8, 16) = 3584 tiles
  gather_kernel<<<ggrid, 256, 0, stream>>>(p1, p2, y1, x1, y2, x2, des1, des2,
                                           row_sum, (float*)d_out, M);

  mfma_lse<<<dim3(NB * NRB * NRB), 256, 0, stream>>>(des1, des2, row_sum,
                                                     col_sum, diagbuf, M);

  finalize<<<(NB * MP) / 256, 256, 0, stream>>>(row_sum, col_sum, diagbuf,
                                                (float*)d_out, M,
                                                (float)(MP - M),
                                                1.f / (float)(NB * M));
}

// Round 5
// 185.367 us; speedup vs baseline: 1.1044x; 1.0229x over previous
//
#include <hip/hip_runtime.h>

#define NB 8
#define NC 256
#define IMG 3600
#define MP 3584         // M padded (multiple of 128)
#define NRB 28          // MP/128 row/col tiles
#define NKB 8           // NC/32 K-tiles of 32
#define SCALE 0.28853901f   // 0.2 * log2(e): exp(0.2*dot) = exp2(SCALE*dot)
#define LN2X2 1.38629436f   // 2*ln2: dist_diag term

typedef unsigned short u16;
typedef __bf16 bf16x8 __attribute__((ext_vector_type(8)));
typedef float  f32x4  __attribute__((ext_vector_type(4)));
typedef unsigned short u16x8 __attribute__((ext_vector_type(8)));

__device__ __forceinline__ u16 f2bf(float f) {
  unsigned u = __builtin_bit_cast(unsigned, f);
  u += 0x7FFFu + ((u >> 16) & 1u);          // round-to-nearest-even
  return (u16)(u >> 16);
}

__device__ __forceinline__ void gld16(const void* g, void* l) {
  __builtin_amdgcn_global_load_lds(
      (__attribute__((address_space(1))) void*)g,
      (__attribute__((address_space(3))) void*)l, 16, 0, 0);
}

// ---------------------------------------------------------------------------
// Gather (v2, unchanged): LDS-staged transpose so BOTH sides coalesce.
//   Block (rb,kb,side*8+b) loads 128 rows x 32 c as 16 per-c-plane coalesced
//   wave loads, packs bf16 into the slot-swizzled tile layout in LDS
//   (slot = ch ^ ((row>>1)&3)), then stores the 8KB tile as 2 contiguous
//   1KB-per-wave dwordx4 stores. Folds row/col-sum + out zeroing.
//   Rows >= M zero-filled (pad correction applied exactly in finalize).
// ---------------------------------------------------------------------------
__global__ __launch_bounds__(256)
void gather_kernel(const float* __restrict__ p1, const float* __restrict__ p2,
                   const int* __restrict__ y1, const int* __restrict__ x1,
                   const int* __restrict__ y2, const int* __restrict__ x2,
                   u16* __restrict__ des1, u16* __restrict__ des2,
                   float* __restrict__ zbase, float* __restrict__ out, int M) {
  __shared__ __align__(16) u16 tile[4096];   // 8 KB: 128 rows x 4 slots x 16B
  const int which = blockIdx.z >> 3, b = blockIdx.z & 7;
  const int kb = blockIdx.y, rb = blockIdx.x;
  const float* P = (which ? p2 : p1) + (size_t)b * NC * IMG;
  const int* Y = which ? y2 : y1;
  const int* X = which ? x2 : x1;
  u16* D = which ? des2 : des1;
  const float sc = which ? 1.f : SCALE;      // A side pre-scaled by SCALE

  const int t = threadIdx.x;

  // fold zeroing of row_sum+col_sum (2*NB*MP contiguous floats) and out
  {
    const int bid = (int)(blockIdx.z * (NKB * NRB) + blockIdx.y * NRB + blockIdx.x);
    const int gi = bid * 256 + t;
    if (gi < 2 * NB * MP) zbase[gi] = 0.f;
    if (gi == 0) *out = 0.f;
  }

  const int row = t & 127, h = t >> 7;       // h selects chunks 2h, 2h+1
  const int m = rb * 128 + row;
  const bool mv = m < M;
  const int pix = mv ? (Y[m] * 60 + X[m]) : 0;
  const float* src = P + (size_t)(kb * 32 + h * 16) * IMG + pix;

  float v[16];                               // 16 c-planes, each wave-coalesced
#pragma unroll
  for (int j = 0; j < 16; ++j) v[j] = mv ? src[(size_t)j * IMG] : 0.f;

  u16x8 lo, hi;
#pragma unroll
  for (int j = 0; j < 8; ++j) lo[j] = f2bf(v[j] * sc);
#pragma unroll
  for (int j = 0; j < 8; ++j) hi[j] = f2bf(v[8 + j] * sc);

  const int sw = (row >> 1) & 3;
  *(u16x8*)&tile[((row * 4) + ((2 * h)     ^ sw)) * 8] = lo;
  *(u16x8*)&tile[((row * 4) + ((2 * h + 1) ^ sw)) * 8] = hi;
  __syncthreads();

  // linear LDS -> linear global: 2 x (64 lanes x 16B contiguous) per wave
  u16* Dt = D + (((size_t)b * NKB + kb) * NRB + rb) * 4096;
  *(u16x8*)(Dt + t * 8)         = *(const u16x8*)&tile[t * 8];
  *(u16x8*)(Dt + (t + 256) * 8) = *(const u16x8*)&tile[(t + 256) * 8];
}

// ---------------------------------------------------------------------------
// MFMA GEMM + fused exp2 / row / col / diag.
// v6 = v1 (the proven 85us structure: 128x128 tile, 4 waves 2x2, 2x16KB LDS
// double buffer, gld16 staging) + exactly two levers from the R4 post-mortem:
//   (1) __launch_bounds__(256, 4): cap unified VGPR+AGPR at 128/wave so the
//       runtime fits 4 blocks/CU (16 waves) instead of v1's 3. Five rounds of
//       evidence say occupancy is the binding resource (MFMA pipe only ~7.5%
//       busy by FLOP math; MfmaUtil's 26% is a gfx94x-formula artifact).
//       Live state ~120 regs (acc 64 AGPR + frags 32 + addr) -> should fit.
//   (2) single barrier per K-step (v2/v3's verified-correct scheme, kept at
//       32KB LDS this time): per iter: vmcnt(0) [drains only stage(k)'s 4
//       loads, issued one full step ago - NOT a fresh-load drain] +
//       lgkmcnt(0) [iter k-1 frag reads; already consumed by MFMAs -> ~free]
//       -> s_barrier -> stage(k+1) into buf[(k+1)&1] [WAR-safe: all waves
//       passed barrier after completing k-1 reads; RAW-safe: each wave's
//       vmcnt(0) preceded its barrier arrival] -> frags k -> 16 MFMAs.
//       Removes 8 barriers + 8 waitcnts per block vs v1.
// Lean epilogue unchanged (verified): bare exp2, no masks (pad rows/cols are
// zero -> exp2(0)=1, exact constant subtracted in finalize). All register
// subscripts COMPILE-TIME. Frag layouts (16x16x32 bf16): A/B[row=l15]
// [k=quad*8+j]; C/D col=l15, row=quad*4+reg. batch = blockIdx&7 -> XCD-pinned.
// ---------------------------------------------------------------------------
__global__ __launch_bounds__(256, 4)
void mfma_lse(const u16* __restrict__ des1, const u16* __restrict__ des2,
              float* __restrict__ row_sum, float* __restrict__ col_sum,
              float* __restrict__ diag, int M) {
  __shared__ __align__(16) u16 bufA[2][4096];   // 8 KB each
  __shared__ __align__(16) u16 bufB[2][4096];

  const int flat = blockIdx.x;
  const int b = flat & 7;
  const int f = flat >> 3;
  const int mt = f % NRB;
  const int nt = (f / NRB + mt) % NRB;          // stagger col-atomic order
  const int m0 = mt * 128, n0 = nt * 128;
  const int t = threadIdx.x;
  const int w = t >> 6, lane = t & 63;
  const int wm = w >> 1, wn = w & 1;
  const int quad = lane >> 4, l15 = lane & 15;

  auto stage = [&](int kb, int sel) {
    const u16* Ak = des1 + (((size_t)b * NKB + kb) * NRB + mt) * 4096;
    const u16* Bk = des2 + (((size_t)b * NKB + kb) * NRB + nt) * 4096;
#pragma unroll
    for (int i = 0; i < 2; ++i) {
      int idx = i * 256 + t;
      gld16(Ak + (size_t)idx * 8, &bufA[sel][idx * 8]);
      gld16(Bk + (size_t)idx * 8, &bufB[sel][idx * 8]);
    }
  };

  f32x4 acc[4][4] = {};

  stage(0, 0);
#pragma unroll
  for (int kb = 0; kb < NKB; ++kb) {
    asm volatile("s_waitcnt vmcnt(0)" ::: "memory");   // stage(kb) resident
    asm volatile("s_waitcnt lgkmcnt(0)" ::: "memory"); // k-1 frag reads done
    asm volatile("s_barrier" ::: "memory");
    if (kb + 1 < NKB) stage(kb + 1, (kb + 1) & 1);     // full step in flight

    const u16* As = bufA[kb & 1];
    const u16* Bs = bufB[kb & 1];
    bf16x8 af[4], bf[4];
#pragma unroll
    for (int i = 0; i < 4; ++i) {
      int row = wm * 64 + i * 16 + l15;
      int slot = quad ^ ((row >> 1) & 3);
      af[i] = *(const bf16x8*)&As[(row * 4 + slot) * 8];
    }
#pragma unroll
    for (int j = 0; j < 4; ++j) {
      int row = wn * 64 + j * 16 + l15;
      int slot = quad ^ ((row >> 1) & 3);
      bf[j] = *(const bf16x8*)&Bs[(row * 4 + slot) * 8];
    }
#pragma unroll
    for (int i = 0; i < 4; ++i)
#pragma unroll
      for (int j = 0; j < 4; ++j)
        acc[i][j] = __builtin_amdgcn_mfma_f32_16x16x32_bf16(
            af[i], bf[j], acc[i][j], 0, 0, 0);
  }

  // ---- lean epilogue: bare exp2, no masks, shuffle-reduced atomics ----
  float cp[4] = {0.f, 0.f, 0.f, 0.f};
#pragma unroll
  for (int i = 0; i < 4; ++i)
#pragma unroll
    for (int r = 0; r < 4; ++r) {
      float rv = 0.f;
#pragma unroll
      for (int j = 0; j < 4; ++j) {
        float e = exp2f(acc[i][j][r]);
        rv += e;
        cp[j] += e;
      }
      rv += __shfl_xor(rv, 1); rv += __shfl_xor(rv, 2);
      rv += __shfl_xor(rv, 4); rv += __shfl_xor(rv, 8);
      if (l15 == 0)
        atomicAdd(&row_sum[(size_t)b * MP + m0 + wm * 64 + i * 16 + quad * 4 + r], rv);
    }
#pragma unroll
  for (int j = 0; j < 4; ++j) {
    float c = cp[j];
    c += __shfl_xor(c, 16); c += __shfl_xor(c, 32);
    if (quad == 0)
      atomicAdd(&col_sum[(size_t)b * MP + n0 + wn * 64 + j * 16 + l15], c);
  }
  if (mt == nt && wm == wn) {
#pragma unroll
    for (int i = 0; i < 4; ++i)
#pragma unroll
      for (int r = 0; r < 4; ++r)
        if (l15 == quad * 4 + r)
          diag[(size_t)b * MP + m0 + wm * 64 + i * 16 + quad * 4 + r] =
              acc[i][i][r];
  }
}

// ---------------------------------------------------------------------------
// loss = mean over valid of log(rs - pad) + log(cs - pad) - 2*ln2*diag'
// pad = MP - M exact (pad rows/cols contributed exp2(0)=1 each).
// ---------------------------------------------------------------------------
__global__ __launch_bounds__(256)
void finalize(const float* __restrict__ row_sum, const float* __restrict__ col_sum,
              const float* __restrict__ diag, float* __restrict__ out,
              int M, float padf, float inv_total) {
  __shared__ float red[4];
  const int i = blockIdx.x * 256 + threadIdx.x;   // over NB*MP
  const int mm = i % MP;
  float s = 0.f;
  if (mm < M)
    s = __logf(row_sum[i] - padf) + __logf(col_sum[i] - padf) - LN2X2 * diag[i];
#pragma unroll
  for (int o = 1; o < 64; o <<= 1) s += __shfl_xor(s, o);
  const int lane = threadIdx.x & 63, wid = threadIdx.x >> 6;
  if (lane == 0) red[wid] = s;
  __syncthreads();
  if (threadIdx.x == 0)
    atomicAdd(out, (red[0] + red[1] + red[2] + red[3]) * inv_total);
}

extern "C" void kernel_launch(void* const* d_in, const int* in_sizes, int n_in,
                              void* d_out, int out_size, void* d_ws, size_t ws_size,
                              hipStream_t stream) {
  const float* p1 = (const float*)d_in[0];
  const float* p2 = (const float*)d_in[1];
  const int* y1 = (const int*)d_in[2];
  const int* x1 = (const int*)d_in[3];
  const int* y2 = (const int*)d_in[4];
  const int* x2 = (const int*)d_in[5];
  const int M = in_sizes[2];                    // 3540 (<= MP)

  float* row_sum = (float*)d_ws;                // NB*MP
  float* col_sum = row_sum + (size_t)NB * MP;   // NB*MP
  float* diagbuf = col_sum + (size_t)NB * MP;   // NB*MP
  size_t off = (((size_t)3 * NB * MP * sizeof(float)) + 255) & ~(size_t)255;
  u16* des1 = (u16*)((char*)d_ws + off);        // NB*MP*NC bf16, tiled+swizzled
  u16* des2 = des1 + (size_t)NB * MP * NC;

  // zeroing of row/col sums + out folded into gather_kernel (fewer graph nodes)
  dim3 ggrid(NRB, NKB, 2 * NB);                 // (28, 8, 16) = 3584 tiles
  gather_kernel<<<ggrid, 256, 0, stream>>>(p1, p2, y1, x1, y2, x2, des1, des2,
                                           row_sum, (float*)d_out, M);

  mfma_lse<<<dim3(NB * NRB * NRB), 256, 0, stream>>>(des1, des2, row_sum,
                                                     col_sum, diagbuf, M);

  finalize<<<(NB * MP) / 256, 256, 0, stream>>>(row_sum, col_sum, diagbuf,
                                                (float*)d_out, M,
                                                (float)(MP - M),
                                                1.f / (float)(NB * M));
}

// Round 6
// 185.014 us; speedup vs baseline: 1.1065x; 1.0019x over previous
//
#include <hip/hip_runtime.h>

#define NB 8
#define NC 256
#define IMG 3600
#define MP 3584         // M padded (multiple of 128)
#define NRB 28          // MP/128 row/col tiles
#define NKB 8           // NC/32 K-tiles of 32
#define SCALE 0.28853901f   // 0.2 * log2(e): exp(0.2*dot) = exp2(SCALE*dot)
#define LN2X2 1.38629436f   // 2*ln2: dist_diag term

typedef unsigned short u16;
typedef __bf16 bf16x8 __attribute__((ext_vector_type(8)));
typedef float  f32x4  __attribute__((ext_vector_type(4)));
typedef unsigned short u16x8 __attribute__((ext_vector_type(8)));

__device__ __forceinline__ u16 f2bf(float f) {
  unsigned u = __builtin_bit_cast(unsigned, f);
  u += 0x7FFFu + ((u >> 16) & 1u);          // round-to-nearest-even
  return (u16)(u >> 16);
}

__device__ __forceinline__ void gld16(const void* g, void* l) {
  __builtin_amdgcn_global_load_lds(
      (__attribute__((address_space(1))) void*)g,
      (__attribute__((address_space(3))) void*)l, 16, 0, 0);
}

// ---------------------------------------------------------------------------
// Gather v3 = v2 + XCD-ALIGNED GRID.
//   R5 finding: mfma_lse reads des[b] from XCD b (flat%8==b by design), but
//   gather v2's 3-D grid mapped tile (b,kb,rb) to XCD (4*kb+rb)%8 -> producer
//   and consumer XCD almost never match -> all 29.4MB of des took an L3/HBM
//   round trip (mfma FETCH 14.4MB + WRITE 31MB) and K-loop gld16s ate
//   L3-miss latency. Fix: 1-D grid, linear id = ((side*NKB+kb)*NRB+rb)*8 + b
//   so id%8 == b: des[b] (3.68MB, fits a 4MB XCD L2) is written by and read
//   from the SAME XCD.
//   Body unchanged (LDS-staged transpose, both sides coalesced; slot-swizzled
//   tile layout slot = ch ^ ((row>>1)&3); folds row/col-sum + out zeroing;
//   rows >= M zero-filled, pad corrected exactly in finalize).
// ---------------------------------------------------------------------------
__global__ __launch_bounds__(256)
void gather_kernel(const float* __restrict__ p1, const float* __restrict__ p2,
                   const int* __restrict__ y1, const int* __restrict__ x1,
                   const int* __restrict__ y2, const int* __restrict__ x2,
                   u16* __restrict__ des1, u16* __restrict__ des2,
                   float* __restrict__ zbase, float* __restrict__ out, int M) {
  __shared__ __align__(16) u16 tile[4096];   // 8 KB: 128 rows x 4 slots x 16B
  const int id = blockIdx.x;
  const int b = id & 7;                      // XCD = id%8 = b (matches reader)
  const int r = id >> 3;
  const int rb = r % NRB;
  const int r2 = r / NRB;
  const int kb = r2 % NKB;
  const int which = r2 / NKB;                // 0 -> des1 (A), 1 -> des2 (B)
  const float* P = (which ? p2 : p1) + (size_t)b * NC * IMG;
  const int* Y = which ? y2 : y1;
  const int* X = which ? x2 : x1;
  u16* D = which ? des2 : des1;
  const float sc = which ? 1.f : SCALE;      // A side pre-scaled by SCALE

  const int t = threadIdx.x;

  // fold zeroing of row_sum+col_sum (2*NB*MP contiguous floats) and out
  {
    const int gi = id * 256 + t;
    if (gi < 2 * NB * MP) zbase[gi] = 0.f;
    if (gi == 0) *out = 0.f;
  }

  const int row = t & 127, h = t >> 7;       // h selects chunks 2h, 2h+1
  const int m = rb * 128 + row;
  const bool mv = m < M;
  const int pix = mv ? (Y[m] * 60 + X[m]) : 0;
  const float* src = P + (size_t)(kb * 32 + h * 16) * IMG + pix;

  float v[16];                               // 16 c-planes, each wave-coalesced
#pragma unroll
  for (int j = 0; j < 16; ++j) v[j] = mv ? src[(size_t)j * IMG] : 0.f;

  u16x8 lo, hi;
#pragma unroll
  for (int j = 0; j < 8; ++j) lo[j] = f2bf(v[j] * sc);
#pragma unroll
  for (int j = 0; j < 8; ++j) hi[j] = f2bf(v[8 + j] * sc);

  const int sw = (row >> 1) & 3;
  *(u16x8*)&tile[((row * 4) + ((2 * h)     ^ sw)) * 8] = lo;
  *(u16x8*)&tile[((row * 4) + ((2 * h + 1) ^ sw)) * 8] = hi;
  __syncthreads();

  // linear LDS -> linear global: 2 x (64 lanes x 16B contiguous) per wave
  u16* Dt = D + (((size_t)b * NKB + kb) * NRB + rb) * 4096;
  *(u16x8*)(Dt + t * 8)         = *(const u16x8*)&tile[t * 8];
  *(u16x8*)(Dt + (t + 256) * 8) = *(const u16x8*)&tile[(t + 256) * 8];
}

// ---------------------------------------------------------------------------
// MFMA GEMM + fused exp2 / row / col / diag.  EXACT v1 (proven 85us, best of
// 6 structural variants tried in R0-R5):  128x128 C-tile, 4 waves 2x2,
// 2x(8+8)KB LDS double buffer, gld16 staging.
//   K-loop per iter: stage(kb+1) EARLY (prefetch issue before any wait) ->
//   s_waitcnt vmcnt(4) (drains stage(kb) only, issued one full iter ago;
//   stage(kb+1) stays in flight -- never vmcnt(0) until last iter) ->
//   s_barrier (all waves' stage(kb) resident) -> frag ds_reads -> 16 MFMAs
//   -> lgkmcnt(0) + s_barrier (all waves done reading buf before it is
//   overwritten next iter).  This 2-barrier form allows the early prefetch
//   issue; R5's 1-barrier variant forces late issue and measured +5us.
//   Occupancy: 60 VGPR + 64 AGPR ~ 124 unified -> 4 waves/SIMD; 32KB LDS ->
//   4 blocks/CU (16 waves).  (R5 recalibration: OccupancyPercent reads
//   ~0.77x theoretical in every config; v1 was already at 4 blocks/CU.)
// Lean epilogue: bare exp2, NO masks (pad rows/cols are zero -> exp2(0)=1,
// exact constant subtracted in finalize). All register-array subscripts
// COMPILE-TIME. Frag layouts (16x16x32 bf16): A/B[row=l15][k=quad*8+j];
// C/D col=l15, row=quad*4+reg.  batch = blockIdx&7 -> XCD-pinned L2 set.
// ---------------------------------------------------------------------------
__global__ __launch_bounds__(256, 2)
void mfma_lse(const u16* __restrict__ des1, const u16* __restrict__ des2,
              float* __restrict__ row_sum, float* __restrict__ col_sum,
              float* __restrict__ diag, int M) {
  __shared__ __align__(16) u16 bufA[2][4096];   // 8 KB each
  __shared__ __align__(16) u16 bufB[2][4096];

  const int flat = blockIdx.x;
  const int b = flat & 7;
  const int f = flat >> 3;
  const int mt = f % NRB;
  const int nt = (f / NRB + mt) % NRB;          // stagger col-atomic order
  const int m0 = mt * 128, n0 = nt * 128;
  const int t = threadIdx.x;
  const int w = t >> 6, lane = t & 63;
  const int wm = w >> 1, wn = w & 1;
  const int quad = lane >> 4, l15 = lane & 15;

  auto stage = [&](int kb, int sel) {
    const u16* Ak = des1 + (((size_t)b * NKB + kb) * NRB + mt) * 4096;
    const u16* Bk = des2 + (((size_t)b * NKB + kb) * NRB + nt) * 4096;
#pragma unroll
    for (int i = 0; i < 2; ++i) {
      int idx = i * 256 + t;
      gld16(Ak + (size_t)idx * 8, &bufA[sel][idx * 8]);
      gld16(Bk + (size_t)idx * 8, &bufB[sel][idx * 8]);
    }
  };

  f32x4 acc[4][4] = {};

  stage(0, 0);
  for (int kb = 0; kb < NKB; ++kb) {
    if (kb + 1 < NKB) {
      stage(kb + 1, (kb + 1) & 1);
      asm volatile("s_waitcnt vmcnt(4)" ::: "memory");   // kb's tile resident
    } else {
      asm volatile("s_waitcnt vmcnt(0)" ::: "memory");
    }
    asm volatile("s_barrier" ::: "memory");

    const u16* As = bufA[kb & 1];
    const u16* Bs = bufB[kb & 1];
    bf16x8 af[4], bf[4];
#pragma unroll
    for (int i = 0; i < 4; ++i) {
      int row = wm * 64 + i * 16 + l15;
      int slot = quad ^ ((row >> 1) & 3);
      af[i] = *(const bf16x8*)&As[(row * 4 + slot) * 8];
    }
#pragma unroll
    for (int j = 0; j < 4; ++j) {
      int row = wn * 64 + j * 16 + l15;
      int slot = quad ^ ((row >> 1) & 3);
      bf[j] = *(const bf16x8*)&Bs[(row * 4 + slot) * 8];
    }
#pragma unroll
    for (int i = 0; i < 4; ++i)
#pragma unroll
      for (int j = 0; j < 4; ++j)
        acc[i][j] = __builtin_amdgcn_mfma_f32_16x16x32_bf16(
            af[i], bf[j], acc[i][j], 0, 0, 0);

    asm volatile("s_waitcnt lgkmcnt(0)" ::: "memory");   // frag reads done
    asm volatile("s_barrier" ::: "memory");              // before overwrite
  }

  // ---- lean epilogue: bare exp2, no masks, shuffle-reduced atomics ----
  float cp[4] = {0.f, 0.f, 0.f, 0.f};
#pragma unroll
  for (int i = 0; i < 4; ++i)
#pragma unroll
    for (int r = 0; r < 4; ++r) {
      float rv = 0.f;
#pragma unroll
      for (int j = 0; j < 4; ++j) {
        float e = exp2f(acc[i][j][r]);
        rv += e;
        cp[j] += e;
      }
      rv += __shfl_xor(rv, 1); rv += __shfl_xor(rv, 2);
      rv += __shfl_xor(rv, 4); rv += __shfl_xor(rv, 8);
      if (l15 == 0)
        atomicAdd(&row_sum[(size_t)b * MP + m0 + wm * 64 + i * 16 + quad * 4 + r], rv);
    }
#pragma unroll
  for (int j = 0; j < 4; ++j) {
    float c = cp[j];
    c += __shfl_xor(c, 16); c += __shfl_xor(c, 32);
    if (quad == 0)
      atomicAdd(&col_sum[(size_t)b * MP + n0 + wn * 64 + j * 16 + l15], c);
  }
  if (mt == nt && wm == wn) {
#pragma unroll
    for (int i = 0; i < 4; ++i)
#pragma unroll
      for (int r = 0; r < 4; ++r)
        if (l15 == quad * 4 + r)
          diag[(size_t)b * MP + m0 + wm * 64 + i * 16 + quad * 4 + r] =
              acc[i][i][r];
  }
}

// ---------------------------------------------------------------------------
// loss = mean over valid of log(rs - pad) + log(cs - pad) - 2*ln2*diag'
// pad = MP - M exact (pad rows/cols contributed exp2(0)=1 each).
// ---------------------------------------------------------------------------
__global__ __launch_bounds__(256)
void finalize(const float* __restrict__ row_sum, const float* __restrict__ col_sum,
              const float* __restrict__ diag, float* __restrict__ out,
              int M, float padf, float inv_total) {
  __shared__ float red[4];
  const int i = blockIdx.x * 256 + threadIdx.x;   // over NB*MP
  const int mm = i % MP;
  float s = 0.f;
  if (mm < M)
    s = __logf(row_sum[i] - padf) + __logf(col_sum[i] - padf) - LN2X2 * diag[i];
#pragma unroll
  for (int o = 1; o < 64; o <<= 1) s += __shfl_xor(s, o);
  const int lane = threadIdx.x & 63, wid = threadIdx.x >> 6;
  if (lane == 0) red[wid] = s;
  __syncthreads();
  if (threadIdx.x == 0)
    atomicAdd(out, (red[0] + red[1] + red[2] + red[3]) * inv_total);
}

extern "C" void kernel_launch(void* const* d_in, const int* in_sizes, int n_in,
                              void* d_out, int out_size, void* d_ws, size_t ws_size,
                              hipStream_t stream) {
  const float* p1 = (const float*)d_in[0];
  const float* p2 = (const float*)d_in[1];
  const int* y1 = (const int*)d_in[2];
  const int* x1 = (const int*)d_in[3];
  const int* y2 = (const int*)d_in[4];
  const int* x2 = (const int*)d_in[5];
  const int M = in_sizes[2];                    // 3540 (<= MP)

  float* row_sum = (float*)d_ws;                // NB*MP
  float* col_sum = row_sum + (size_t)NB * MP;   // NB*MP
  float* diagbuf = col_sum + (size_t)NB * MP;   // NB*MP
  size_t off = (((size_t)3 * NB * MP * sizeof(float)) + 255) & ~(size_t)255;
  u16* des1 = (u16*)((char*)d_ws + off);        // NB*MP*NC bf16, tiled+swizzled
  u16* des2 = des1 + (size_t)NB * MP * NC;

  // zeroing of row/col sums + out folded into gather_kernel (fewer graph nodes)
  // 1-D grid: id%8 == b -> gather writes des[b] on the XCD that reads it
  gather_kernel<<<dim3(2 * NKB * NRB * 8), 256, 0, stream>>>(
      p1, p2, y1, x1, y2, x2, des1, des2, row_sum, (float*)d_out, M);

  mfma_lse<<<dim3(NB * NRB * NRB), 256, 0, stream>>>(des1, des2, row_sum,
                                                     col_sum, diagbuf, M);

  finalize<<<(NB * MP) / 256, 256, 0, stream>>>(row_sum, col_sum, diagbuf,
                                                (float*)d_out, M,
                                                (float)(MP - M),
                                                1.f / (float)(NB * M));
}

// Round 7
// 177.268 us; speedup vs baseline: 1.1549x; 1.0437x over previous
//
#include <hip/hip_runtime.h>

#define NB 8
#define NC 256
#define IMG 3600
#define MP 3584         // M padded (multiple of 128)
#define NRB 28          // MP/128 row/col tiles
#define NKB 8           // NC/32 K-tiles of 32
#define SCALE 0.28853901f   // 0.2 * log2(e): exp(0.2*dot) = exp2(SCALE*dot)
#define LN2X2 1.38629436f   // 2*ln2: dist_diag term

typedef unsigned short u16;
typedef __bf16 bf16x8 __attribute__((ext_vector_type(8)));
typedef float  f32x4  __attribute__((ext_vector_type(4)));
typedef unsigned short u16x8 __attribute__((ext_vector_type(8)));

__device__ __forceinline__ u16 f2bf(float f) {
  unsigned u = __builtin_bit_cast(unsigned, f);
  u += 0x7FFFu + ((u >> 16) & 1u);          // round-to-nearest-even
  return (u16)(u >> 16);
}

__device__ __forceinline__ void gld16(const void* g, void* l) {
  __builtin_amdgcn_global_load_lds(
      (__attribute__((address_space(1))) void*)g,
      (__attribute__((address_space(3))) void*)l, 16, 0, 0);
}

// ---------------------------------------------------------------------------
// Gather v3 (unchanged from R5): LDS-staged transpose, both sides coalesced,
// XCD-aligned 1-D grid (id%8 == b), slot-swizzled tile layout
// slot = ch ^ ((row>>1)&3), folds row/col-sum + out zeroing.
// Rows >= M zero-filled (pad correction applied exactly in finalize).
// ---------------------------------------------------------------------------
__global__ __launch_bounds__(256)
void gather_kernel(const float* __restrict__ p1, const float* __restrict__ p2,
                   const int* __restrict__ y1, const int* __restrict__ x1,
                   const int* __restrict__ y2, const int* __restrict__ x2,
                   u16* __restrict__ des1, u16* __restrict__ des2,
                   float* __restrict__ zbase, float* __restrict__ out, int M) {
  __shared__ __align__(16) u16 tile[4096];   // 8 KB: 128 rows x 4 slots x 16B
  const int id = blockIdx.x;
  const int b = id & 7;                      // XCD = id%8 = b (matches reader)
  const int r = id >> 3;
  const int rb = r % NRB;
  const int r2 = r / NRB;
  const int kb = r2 % NKB;
  const int which = r2 / NKB;                // 0 -> des1 (A), 1 -> des2 (B)
  const float* P = (which ? p2 : p1) + (size_t)b * NC * IMG;
  const int* Y = which ? y2 : y1;
  const int* X = which ? x2 : x1;
  u16* D = which ? des2 : des1;
  const float sc = which ? 1.f : SCALE;      // A side pre-scaled by SCALE

  const int t = threadIdx.x;

  // fold zeroing of row_sum+col_sum (2*NB*MP contiguous floats) and out
  {
    const int gi = id * 256 + t;
    if (gi < 2 * NB * MP) zbase[gi] = 0.f;
    if (gi == 0) *out = 0.f;
  }

  const int row = t & 127, h = t >> 7;       // h selects chunks 2h, 2h+1
  const int m = rb * 128 + row;
  const bool mv = m < M;
  const int pix = mv ? (Y[m] * 60 + X[m]) : 0;
  const float* src = P + (size_t)(kb * 32 + h * 16) * IMG + pix;

  float v[16];                               // 16 c-planes, each wave-coalesced
#pragma unroll
  for (int j = 0; j < 16; ++j) v[j] = mv ? src[(size_t)j * IMG] : 0.f;

  u16x8 lo, hi;
#pragma unroll
  for (int j = 0; j < 8; ++j) lo[j] = f2bf(v[j] * sc);
#pragma unroll
  for (int j = 0; j < 8; ++j) hi[j] = f2bf(v[8 + j] * sc);

  const int sw = (row >> 1) & 3;
  *(u16x8*)&tile[((row * 4) + ((2 * h)     ^ sw)) * 8] = lo;
  *(u16x8*)&tile[((row * 4) + ((2 * h + 1) ^ sw)) * 8] = hi;
  __syncthreads();

  // linear LDS -> linear global: 2 x (64 lanes x 16B contiguous) per wave
  u16* Dt = D + (((size_t)b * NKB + kb) * NRB + rb) * 4096;
  *(u16x8*)(Dt + t * 8)         = *(const u16x8*)&tile[t * 8];
  *(u16x8*)(Dt + (t + 256) * 8) = *(const u16x8*)&tile[(t + 256) * 8];
}

// ---------------------------------------------------------------------------
// MFMA GEMM + fused exp2 / row / col / diag.
// v8: HALVE THE LDS PIPE (R6 model: 128 ds_read_b128/CU-step = 1536 cyc
// serialized through one LDS unit is the binding term).
//   * B side NEVER touches LDS: fragments load directly from L2 into VGPRs
//     (v5's proven flatmm addressing: offB = row*64 + slot*16 with slot
//     i-invariant -> each load's 64 lanes cover one contiguous 1KB block),
//     register double-buffered one K-step ahead. The 2x B duplication
//     between wm=0/1 waves is ~100 cyc apart on an 8KB working set -> L1.
//   * A side stays gld16->LDS (shared by both wn waves) but fragments are
//     STREAMED through one 4-reg temp (read af_i -> 4 MFMAs -> reuse),
//     freeing 12 regs to pay for the B double-buffer.
//   * 3-buffer A + SINGLE barrier per K-step with EARLY prefetch:
//     iter k: stage(k+1)->bufA[(k+1)%3] (2 gld16) + loadB(k+1)->bfr[(k+1)&1]
//     issued at top -> s_waitcnt vmcnt(6) (drains stage(k)'s 2 + B(k)'s 4;
//     the 6 just-issued stay in flight; never vmcnt(0) until last iter) ->
//     s_barrier -> {ds_read af_i; 4 MFMA} x4.
//     WAR-safe: bufA[(k+1)%3] was last read at step k-2; those reads were
//     consumed by MFMA(k-2) (compiler lgkm) before every wave arrived at
//     barrier(k-1), which I passed before this issue. RAW-safe: each wave's
//     vmcnt(6) precedes its barrier arrival -> post-barrier the A tile is
//     complete and own B regs are ready.
//   Registers: acc 64 + bfr 32 + af 4 + addressing ~20 = ~120 unified;
//   __launch_bounds__(256,4) caps at 128 -> 16 waves/CU (the occupancy all
//   7 rounds agree is mandatory). LDS 3x8KB = 24KB. kb loop fully unrolled
//   (register-array subscripts compile-time; rule #20).
// Lean epilogue unchanged (verified): bare exp2, no masks, pad handled in
// finalize. Frag layouts (16x16x32 bf16): A/B[row=l15][k=quad*8+j]; C/D
// col=l15, row=quad*4+reg. batch = blockIdx&7 -> XCD-pinned L2 set.
// ---------------------------------------------------------------------------
__global__ __launch_bounds__(256, 4)
void mfma_lse(const u16* __restrict__ des1, const u16* __restrict__ des2,
              float* __restrict__ row_sum, float* __restrict__ col_sum,
              float* __restrict__ diag, int M) {
  __shared__ __align__(16) u16 bufA[3][4096];   // 8 KB each, 24 KB total

  const int flat = blockIdx.x;
  const int b = flat & 7;
  const int f = flat >> 3;
  const int mt = f % NRB;
  const int nt = (f / NRB + mt) % NRB;          // stagger col-atomic order
  const int m0 = mt * 128, n0 = nt * 128;
  const int t = threadIdx.x;
  const int w = t >> 6, lane = t & 63;
  const int wm = w >> 1, wn = w & 1;
  const int quad = lane >> 4, l15 = lane & 15;

  // ---- A: global -> LDS staging (2 gld16/thread per step) ----
  auto stage = [&](int kb, int sel) {
    const u16* Ak = des1 + (((size_t)b * NKB + kb) * NRB + mt) * 4096;
#pragma unroll
    for (int i = 0; i < 2; ++i) {
      int idx = i * 256 + t;
      gld16(Ak + (size_t)idx * 8, &bufA[sel][idx * 8]);
    }
  };

  // ---- B: global -> VGPR fragments (v5-proven addressing) ----
  const int rbw = wn * 64 + l15;
  const int offB = rbw * 64 + (quad ^ ((rbw >> 1) & 3)) * 16;  // bytes
  const char* Bbase =
      (const char*)(des2 + (((size_t)b * NKB) * NRB + nt) * 4096) + offB;
  const size_t kstride = (size_t)NRB * 4096 * sizeof(u16);     // bytes per kb

  bf16x8 bfr[2][4];
  auto loadB = [&](int kb, int sel) {
    const char* Bk = Bbase + (size_t)kb * kstride;
#pragma unroll
    for (int j = 0; j < 4; ++j)
      bfr[sel][j] = *(const bf16x8*)(Bk + j * 1024);
  };

  // per-lane A-frag LDS byte offset (slot is i-invariant: (16i)>>1 ≡ 0 mod 4)
  const int rowA = wm * 64 + l15;
  const int offA = rowA * 64 + (quad ^ ((rowA >> 1) & 3)) * 16;  // bytes

  f32x4 acc[4][4] = {};

  stage(0, 0);
  loadB(0, 0);
#pragma unroll
  for (int kb = 0; kb < NKB; ++kb) {
    if (kb + 1 < NKB) {
      stage(kb + 1, (kb + 1) % 3);
      loadB(kb + 1, (kb + 1) & 1);
      asm volatile("s_waitcnt vmcnt(6)" ::: "memory");  // stage(kb)+B(kb) done
    } else {
      asm volatile("s_waitcnt vmcnt(0)" ::: "memory");
    }
    asm volatile("s_barrier" ::: "memory");             // A tile kb complete

    const char* As = (const char*)bufA[kb % 3] + offA;
    const int s = kb & 1;
#pragma unroll
    for (int i = 0; i < 4; ++i) {
      bf16x8 af = *(const bf16x8*)(As + i * 1024);      // stream A frag i
#pragma unroll
      for (int j = 0; j < 4; ++j)
        acc[i][j] = __builtin_amdgcn_mfma_f32_16x16x32_bf16(
            af, bfr[s][j], acc[i][j], 0, 0, 0);
    }
  }

  // ---- lean epilogue: bare exp2, no masks, shuffle-reduced atomics ----
  float cp[4] = {0.f, 0.f, 0.f, 0.f};
#pragma unroll
  for (int i = 0; i < 4; ++i)
#pragma unroll
    for (int r = 0; r < 4; ++r) {
      float rv = 0.f;
#pragma unroll
      for (int j = 0; j < 4; ++j) {
        float e = exp2f(acc[i][j][r]);
        rv += e;
        cp[j] += e;
      }
      rv += __shfl_xor(rv, 1); rv += __shfl_xor(rv, 2);
      rv += __shfl_xor(rv, 4); rv += __shfl_xor(rv, 8);
      if (l15 == 0)
        atomicAdd(&row_sum[(size_t)b * MP + m0 + wm * 64 + i * 16 + quad * 4 + r], rv);
    }
#pragma unroll
  for (int j = 0; j < 4; ++j) {
    float c = cp[j];
    c += __shfl_xor(c, 16); c += __shfl_xor(c, 32);
    if (quad == 0)
      atomicAdd(&col_sum[(size_t)b * MP + n0 + wn * 64 + j * 16 + l15], c);
  }
  if (mt == nt && wm == wn) {
#pragma unroll
    for (int i = 0; i < 4; ++i)
#pragma unroll
      for (int r = 0; r < 4; ++r)
        if (l15 == quad * 4 + r)
          diag[(size_t)b * MP + m0 + wm * 64 + i * 16 + quad * 4 + r] =
              acc[i][i][r];
  }
}

// ---------------------------------------------------------------------------
// loss = mean over valid of log(rs - pad) + log(cs - pad) - 2*ln2*diag'
// pad = MP - M exact (pad rows/cols contributed exp2(0)=1 each).
// ---------------------------------------------------------------------------
__global__ __launch_bounds__(256)
void finalize(const float* __restrict__ row_sum, const float* __restrict__ col_sum,
              const float* __restrict__ diag, float* __restrict__ out,
              int M, float padf, float inv_total) {
  __shared__ float red[4];
  const int i = blockIdx.x * 256 + threadIdx.x;   // over NB*MP
  const int mm = i % MP;
  float s = 0.f;
  if (mm < M)
    s = __logf(row_sum[i] - padf) + __logf(col_sum[i] - padf) - LN2X2 * diag[i];
#pragma unroll
  for (int o = 1; o < 64; o <<= 1) s += __shfl_xor(s, o);
  const int lane = threadIdx.x & 63, wid = threadIdx.x >> 6;
  if (lane == 0) red[wid] = s;
  __syncthreads();
  if (threadIdx.x == 0)
    atomicAdd(out, (red[0] + red[1] + red[2] + red[3]) * inv_total);
}

extern "C" void kernel_launch(void* const* d_in, const int* in_sizes, int n_in,
                              void* d_out, int out_size, void* d_ws, size_t ws_size,
                              hipStream_t stream) {
  const float* p1 = (const float*)d_in[0];
  const float* p2 = (const float*)d_in[1];
  const int* y1 = (const int*)d_in[2];
  const int* x1 = (const int*)d_in[3];
  const int* y2 = (const int*)d_in[4];
  const int* x2 = (const int*)d_in[5];
  const int M = in_sizes[2];                    // 3540 (<= MP)

  float* row_sum = (float*)d_ws;                // NB*MP
  float* col_sum = row_sum + (size_t)NB * MP;   // NB*MP
  float* diagbuf = col_sum + (size_t)NB * MP;   // NB*MP
  size_t off = (((size_t)3 * NB * MP * sizeof(float)) + 255) & ~(size_t)255;
  u16* des1 = (u16*)((char*)d_ws + off);        // NB*MP*NC bf16, tiled+swizzled
  u16* des2 = des1 + (size_t)NB * MP * NC;

  // zeroing of row/col sums + out folded into gather_kernel (fewer graph nodes)
  // 1-D grid: id%8 == b -> gather writes des[b] on the XCD that reads it
  gather_kernel<<<dim3(2 * NKB * NRB * 8), 256, 0, stream>>>(
      p1, p2, y1, x1, y2, x2, des1, des2, row_sum, (float*)d_out, M);

  mfma_lse<<<dim3(NB * NRB * NRB), 256, 0, stream>>>(des1, des2, row_sum,
                                                     col_sum, diagbuf, M);

  finalize<<<(NB * MP) / 256, 256, 0, stream>>>(row_sum, col_sum, diagbuf,
                                                (float*)d_out, M,
                                                (float)(MP - M),
                                                1.f / (float)(NB * M));
}